// Round 20
// baseline (114.964 us; speedup 1.0000x reference)
//
#include <hip/hip_runtime.h>
#include <stdint.h>

// int4 grouped-quant GEMM: out[64][28672] = x[64][8192] . W^T + bias
// W packed [N][K/2] int32, one byte/int32 = 2 nibbles (low = even k), zp = 8,
// per-128-k scales. fp16 ref -> harness gives x/scales/bias/out as FP32.
// Round-20: RING-4 W pipeline, collapse-proof. R19 found per-block delivery
// = (in-flight W)/period exactly (32 KB -> 10.5 GB/s); R12's depth attempt
// collapsed because X-register waits (in-order vmcnt) forced older W stages
// complete. Fix: unroll x4 with static slots + 4 named X reg-sets; issue
// X(j+4) AFTER W(j+3) so the X(j) wait at compute(j) is older than W(j) ->
// W(j+1..j+3) = 48 KB stays in flight across all barriers. NT on W kept.

typedef __attribute__((ext_vector_type(8))) short     short8;
typedef __attribute__((ext_vector_type(4))) float     f32x4;
typedef __attribute__((ext_vector_type(4))) int       i32x4;
typedef __attribute__((ext_vector_type(2))) _Float16  f16x2;
typedef __attribute__((ext_vector_type(8))) _Float16  f16x8;

// async global->LDS, 16 B/lane; NT (CPol bit1) for the once-read W stream.
static __device__ __forceinline__ void gload_lds16_nt(const void* gp, void* lp) {
    __builtin_amdgcn_global_load_lds(
        (const __attribute__((address_space(1))) unsigned int*)gp,
        (__attribute__((address_space(3))) unsigned int*)lp, 16, 0, 2);
}

// int4 pair -> fp16 pair: u = 0x6400|nib (fp16 1024+v, exact), (u-1032) exact
// in f16 (= v-8), then *s (single rounding - matches reference fp16 mul).
static __device__ __forceinline__ f16x8 dequant(const i32x4& w, f16x2 s2) {
    const f16x2 c1032 = {(_Float16)1032.0f, (_Float16)1032.0f};
    union { unsigned u[4]; f16x8 v; } r;
    #pragma unroll
    for (int j = 0; j < 4; ++j) {
        unsigned v = (unsigned)w[j];
        unsigned u = ((v & 0xFu) | 0x64006400u) | ((v << 12) & 0xF0000u);
        f16x2 h = __builtin_bit_cast(f16x2, u);
        h = (h - c1032) * s2;
        r.u[j] = __builtin_bit_cast(unsigned, h);
    }
    return r.v;
}

// x fp32 [64][K] -> fp16 (lossless) in A-fragment order: xf[g][st][mt][lane][8]
__global__ __launch_bounds__(256)
void xpack_kernel(const float* __restrict__ x, unsigned short* __restrict__ xf, int K) {
    int c    = blockIdx.x * 256 + threadIdx.x;
    int g    = c >> 10;
    int st   = (c >> 8) & 3;
    int mt   = (c >> 6) & 3;
    int lane = c & 63;
    int quad = lane >> 4, l15 = lane & 15;
    const float* p = x + (size_t)(l15 + mt * 16) * K + g * 128 + st * 32 + quad * 8;
    f32x4 lo = *(const f32x4*)p;
    f32x4 hi = *(const f32x4*)(p + 4);
    f16x8 r = { (_Float16)lo[0], (_Float16)lo[1], (_Float16)lo[2], (_Float16)lo[3],
                (_Float16)hi[0], (_Float16)hi[1], (_Float16)hi[2], (_Float16)hi[3] };
    *(short8*)(xf + (size_t)c * 8) = __builtin_bit_cast(short8, r);
}

__global__ __launch_bounds__(256, 2)
void int4mm_kernel(const unsigned short* __restrict__ xf,  // fp16 frag-ordered x
                   const int*   __restrict__ wp,           // [N][K/2]
                   const float* __restrict__ sc,           // [N][ng]
                   const float* __restrict__ bias,         // [N]
                   float*       __restrict__ out,          // [64][N]
                   int K, int N)
{
    __shared__ char lds[81920];              // 64 KB W ring (4 slots) | 16 KB scales
    char*  ldsW = lds;                       // slot s: [64 col][16 chunk][16 B]
    float* ldsS = (float*)(lds + 65536);     // [64 g][64 col]
    // (epilogue reuses ldsW, 48 KB)

    const int tid  = threadIdx.x;
    const int lane = tid & 63;
    const int wave = tid >> 6;               // kstep owner: k-quarter of each group
    const int quad = lane >> 4;
    const int l15  = lane & 15;
    const int blk64 = blockIdx.x * 64;
    const int ng   = K / 128;                // 64 groups (ng % 4 == 0)

    const char* wp8 = (const char*)wp;       // one col's W row = 16384 B

    // W stage sources (R11-verified involution): instr j covers cols
    // wave*16 + j*4 + quad; lane supplies global chunk l15^(j*4+quad);
    // LDS slot s of col c ends up holding chunk s^(c&15).
    unsigned woff[4];
    #pragma unroll
    for (int j = 0; j < 4; ++j) {
        const int cloc  = wave * 16 + j * 4 + quad;
        const int chunk = l15 ^ (j * 4 + quad);
        woff[j] = ((unsigned)(blk64 + cloc) << 14) + ((unsigned)chunk << 4);
    }

    // B-frag ds_read: col c = nt*16+l15, chunk q = wave*4+quad at slot q^l15.
    const int q = wave * 4 + quad;
    int rdW[4];
    #pragma unroll
    for (int nt = 0; nt < 4; ++nt)
        rdW[nt] = (nt * 16 + l15) * 256 + ((q ^ l15) << 4);

    // ---- prologue ----
    // scales: ldsS[g][c] = sc[(blk64+c)*ng + g] via 64 B contiguous loads.
    {
        const int c  = tid & 63;
        const int g0 = (tid >> 6) * 16;
        const float* sp = sc + (size_t)(blk64 + c) * ng + g0;
        f32x4 s0 = *(const f32x4*)(sp);
        f32x4 s1 = *(const f32x4*)(sp + 4);
        f32x4 s2 = *(const f32x4*)(sp + 8);
        f32x4 s3 = *(const f32x4*)(sp + 12);
        #pragma unroll
        for (int j = 0; j < 4; ++j) {
            ldsS[(g0 + 0  + j) * 64 + c] = s0[j];
            ldsS[(g0 + 4  + j) * 64 + c] = s1[j];
            ldsS[(g0 + 8  + j) * 64 + c] = s2[j];
            ldsS[(g0 + 12 + j) * 64 + c] = s3[j];
        }
    }
    #pragma unroll
    for (int g = 0; g < 3; ++g)              // stage W(0..2) -> slots 0..2 (NT)
        #pragma unroll
        for (int j = 0; j < 4; ++j)
            gload_lds16_nt(wp8 + woff[j] + (size_t)g * 256,
                           ldsW + g * 16384 + (wave * 4 + j) * 1024);

    const char* xbase = (const char*)xf + wave * 4096 + lane * 16;
    f16x8 xA[4], xB[4], xC[4], xD[4];        // X(j), X(j+1), X(j+2), X(j+3)
    #pragma unroll
    for (int mt = 0; mt < 4; ++mt) {
        xA[mt] = *(const f16x8*)(xbase +         mt * 1024);
        xB[mt] = *(const f16x8*)(xbase + 16384 + mt * 1024);
        xC[mt] = *(const f16x8*)(xbase + 32768 + mt * 1024);
        xD[mt] = *(const f16x8*)(xbase + 49152 + mt * 1024);
    }

    f32x4 acc[4][4];
    #pragma unroll
    for (int mt = 0; mt < 4; ++mt)
        #pragma unroll
        for (int nt = 0; nt < 4; ++nt)
            acc[mt][nt] = f32x4{0.f, 0.f, 0.f, 0.f};

    __syncthreads();   // prologue drain: scales + W(0..2) + X(0..3) landed

    // Sub-iteration j: barrier; stage W(j+3)->slot (j+3)&3 (freed by
    // compute(j-1)); vmcnt(24) forces W(j) (28 outstanding, oldest 4) while
    // W(j+1..j+3)+X stay in flight; barrier; compute slot j&3 with X-set;
    // then issue X(j+4) into the just-consumed X regs (AFTER W(j+3) in
    // program order, so its future wait never drags younger W stages).
#define SUBITER(J, SLOTC, SLOTS, XS)                                          \
    {                                                                         \
        const int j_  = (J);                                                  \
        const int gw  = (j_ + 3 < ng) ? j_ + 3 : ng - 1;                      \
        const int gx  = (j_ + 4 < ng) ? j_ + 4 : ng - 1;                      \
        __builtin_amdgcn_s_barrier();                                         \
        _Pragma("unroll")                                                     \
        for (int j2 = 0; j2 < 4; ++j2)                                        \
            gload_lds16_nt(wp8 + woff[j2] + (size_t)gw * 256,                 \
                           ldsW + (SLOTS) * 16384 + (wave * 4 + j2) * 1024);  \
        asm volatile("s_waitcnt vmcnt(24)" ::: "memory");                     \
        __builtin_amdgcn_s_barrier();                                         \
        __builtin_amdgcn_sched_barrier(0);                                    \
        const char* wb_ = ldsW + (SLOTC) * 16384;                             \
        i32x4 v0_ = *(const i32x4*)(wb_ + rdW[0]);                            \
        i32x4 v1_ = *(const i32x4*)(wb_ + rdW[1]);                            \
        i32x4 v2_ = *(const i32x4*)(wb_ + rdW[2]);                            \
        i32x4 v3_ = *(const i32x4*)(wb_ + rdW[3]);                            \
        const float* sg_ = ldsS + j_ * 64;                                    \
        const float sf0_ = sg_[l15],      sf1_ = sg_[16 + l15];               \
        const float sf2_ = sg_[32 + l15], sf3_ = sg_[48 + l15];               \
        {                                                                     \
            f16x8 b_ = dequant(v0_, f16x2{(_Float16)sf0_, (_Float16)sf0_});   \
            _Pragma("unroll")                                                 \
            for (int mt = 0; mt < 4; ++mt)                                    \
                acc[mt][0] = __builtin_amdgcn_mfma_f32_16x16x32_f16(          \
                                 XS[mt], b_, acc[mt][0], 0, 0, 0);            \
        }                                                                     \
        {                                                                     \
            f16x8 b_ = dequant(v1_, f16x2{(_Float16)sf1_, (_Float16)sf1_});   \
            _Pragma("unroll")                                                 \
            for (int mt = 0; mt < 4; ++mt)                                    \
                acc[mt][1] = __builtin_amdgcn_mfma_f32_16x16x32_f16(          \
                                 XS[mt], b_, acc[mt][1], 0, 0, 0);            \
        }                                                                     \
        {                                                                     \
            f16x8 b_ = dequant(v2_, f16x2{(_Float16)sf2_, (_Float16)sf2_});   \
            _Pragma("unroll")                                                 \
            for (int mt = 0; mt < 4; ++mt)                                    \
                acc[mt][2] = __builtin_amdgcn_mfma_f32_16x16x32_f16(          \
                                 XS[mt], b_, acc[mt][2], 0, 0, 0);            \
        }                                                                     \
        {                                                                     \
            f16x8 b_ = dequant(v3_, f16x2{(_Float16)sf3_, (_Float16)sf3_});   \
            _Pragma("unroll")                                                 \
            for (int mt = 0; mt < 4; ++mt)                                    \
                acc[mt][3] = __builtin_amdgcn_mfma_f32_16x16x32_f16(          \
                                 XS[mt], b_, acc[mt][3], 0, 0, 0);            \
        }                                                                     \
        const char* xs_ = xbase + (size_t)gx * 16384;                         \
        _Pragma("unroll")                                                     \
        for (int mt = 0; mt < 4; ++mt)                                        \
            XS[mt] = *(const f16x8*)(xs_ + mt * 1024);                        \
    }

    #pragma unroll 1
    for (int g4 = 0; g4 < ng; g4 += 4) {
        SUBITER(g4 + 0, 0, 3, xA)
        SUBITER(g4 + 1, 1, 0, xB)
        SUBITER(g4 + 2, 2, 1, xC)
        SUBITER(g4 + 3, 3, 2, xD)
    }
#undef SUBITER

    // ---- epilogue: cross-wave (kstep) reduce. Wave w owns mt = w. ----
    // Partials: addr(owner o, slot s, nt) = ((o*3+s)*4+nt)*1024 + lane*16 (48 KB).
    __syncthreads();
    #pragma unroll
    for (int o = 0; o < 4; ++o) {
        if (o == wave) continue;             // wave-uniform branch
        const int s = wave - (wave > o ? 1 : 0);
        #pragma unroll
        for (int nt = 0; nt < 4; ++nt)
            *(f32x4*)(lds + (size_t)(((o * 3 + s) * 4 + nt) * 1024) + lane * 16)
                = acc[o][nt];
    }
    __syncthreads();

    f32x4 own[4];
    #pragma unroll
    for (int nt = 0; nt < 4; ++nt) own[nt] = acc[0][nt];
    #pragma unroll
    for (int o = 1; o < 4; ++o)
        if (wave == o) {                     // wave-uniform, compile-time acc idx
            own[0] = acc[o][0]; own[1] = acc[o][1];
            own[2] = acc[o][2]; own[3] = acc[o][3];
        }
    #pragma unroll
    for (int s = 0; s < 3; ++s)
        #pragma unroll
        for (int nt = 0; nt < 4; ++nt)
            own[nt] += *(const f32x4*)(lds + (size_t)(((wave * 3 + s) * 4 + nt) * 1024)
                                       + lane * 16);

    #pragma unroll
    for (int nt = 0; nt < 4; ++nt) {
        const int col = blk64 + nt * 16 + l15;
        const float bv = bias[col];
        #pragma unroll
        for (int r = 0; r < 4; ++r)
            out[(size_t)(wave * 16 + quad * 4 + r) * N + col] = own[nt][r] + bv;
    }
}

extern "C" void kernel_launch(void* const* d_in, const int* in_sizes, int n_in,
                              void* d_out, int out_size, void* d_ws, size_t ws_size,
                              hipStream_t stream)
{
    const float* x    = (const float*)d_in[0];
    const int*   wp   = (const int*)d_in[1];
    const float* sc   = (const float*)d_in[2];
    const float* bias = (const float*)d_in[3];
    float*       out  = (float*)d_out;

    const int N  = in_sizes[3];                       // 28672
    const long long Kh = (long long)in_sizes[1] / N;  // 4096
    const int K  = (int)(2 * Kh);                     // 8192
    const int ng = K / 128;                           // 64

    unsigned short* xf = (unsigned short*)d_ws;       // 1 MB frag-ordered fp16 x

    xpack_kernel<<<(ng * 1024) / 256, 256, 0, stream>>>(x, xf, K);
    int4mm_kernel<<<N / 64, 256, 0, stream>>>(xf, wp, sc, bias, out, K, N);
}